// Round 9
// baseline (560.271 us; speedup 1.0000x reference)
//
#include <hip/hip_runtime.h>

typedef __attribute__((ext_vector_type(8))) short bf16x8;
typedef __attribute__((ext_vector_type(8))) unsigned short ushort8;
typedef __attribute__((ext_vector_type(4))) unsigned short ushort4v;
typedef __attribute__((ext_vector_type(4))) float f32x4;
typedef __attribute__((ext_vector_type(4))) float float4v;
typedef __attribute__((ext_vector_type(8))) _Float16 f16x8;

__device__ inline unsigned short f2bf(float f){
  unsigned u = __builtin_bit_cast(unsigned, f);
  return (unsigned short)((u + 0x7fffu + ((u>>16)&1u)) >> 16);
}
__device__ inline float bf2f(unsigned short h){
  return __builtin_bit_cast(float, (unsigned)h << 16);
}
__device__ inline unsigned short f2h(float f){
  return __builtin_bit_cast(unsigned short, (_Float16)f);
}
__device__ inline float h2f(unsigned short u){
  return (float)__builtin_bit_cast(_Float16, u);
}

__device__ inline void gll16(const void* g, void* l){
  __builtin_amdgcn_global_load_lds((const __attribute__((address_space(1))) void*)g,
                                   (__attribute__((address_space(3))) void*)l, 16, 0, 0);
}

// ---------------- LayerNorm: one wave per row, float4 loads
__global__ __launch_bounds__(256) void k_ln(const float* __restrict__ x,
                                            const float* __restrict__ g,
                                            unsigned short* __restrict__ A3){
  int wid = threadIdx.x >> 6, lane = threadIdx.x & 63;
  int row = blockIdx.x*4 + wid;
  float4v v = *(const float4v*)&x[(size_t)row*256 + lane*4];
  float4v gv = *(const float4v*)&g[lane*4];
  float s  = v[0]+v[1]+v[2]+v[3];
  float s2 = v[0]*v[0]+v[1]*v[1]+v[2]*v[2]+v[3]*v[3];
  #pragma unroll
  for (int m=32; m>=1; m>>=1){ s += __shfl_xor(s, m, 64); s2 += __shfl_xor(s2, m, 64); }
  float mu  = s*(1.f/256.f);
  float var = s2*(1.f/256.f) - mu*mu;
  float rst = rsqrtf(var + 1e-6f);
  ushort4v o;
  #pragma unroll
  for (int e=0;e<4;e++) o[e] = f2bf((v[e]-mu)*rst*gv[e]);
  *(ushort4v*)&A3[(size_t)row*512 + lane*4] = o;
}

// ---------------- column means of x_norm per image
__global__ __launch_bounds__(256) void k_cm1(const unsigned short* __restrict__ A3,
                                             float* __restrict__ psum){
  int blk = blockIdx.x;
  int c = threadIdx.x;
  const unsigned short* base = A3 + (size_t)blk*256*512;
  float s = 0.f;
  for (int p=0;p<256;p++) s += bf2f(base[(size_t)p*512 + c]);
  psum[blk*256 + c] = s;
}
__global__ __launch_bounds__(256) void k_cm2(const float* __restrict__ psum,
                                             float* __restrict__ m){
  int b = blockIdx.x, c = threadIdx.x;
  float s = 0.f;
  for (int ch=0; ch<64; ch++) s += psum[(b*64+ch)*256 + c];
  m[b*256 + c] = s*(1.f/16384.f);
}

// ---------------- weight transposes to bf16 (Bt layout [N][K]) for the two GEMMs
__global__ __launch_bounds__(256) void k_prep_nt(const float* __restrict__ W,
                                                 unsigned short* __restrict__ WT, int K){
  int idx = blockIdx.x*256 + threadIdx.x;
  int j = idx / K, k = idx - j*K;
  WT[idx] = f2bf(W[(size_t)k*256 + j]);
}

// geo weights -> FP16 in panel layout [10][8 k32][4 q][256 n][8 e]
__global__ __launch_bounds__(256) void k_prep_geoT(const float* __restrict__ wl,
                                                   const float* __restrict__ wg,
                                                   unsigned short* __restrict__ WT){
  int idx = blockIdx.x*256 + threadIdx.x;     // over 10*65536, output-linear
  int e = idx & 7, n = (idx>>3)&255, q = (idx>>11)&3, k32 = (idx>>13)&7, sg = idx>>16;
  int k = k32*32 + q*8 + e;
  int j = n;
  float v;
  if (sg < 8){
    int si = sg >> 1, s = 1 << si;
    bool neg = sg & 1;
    int krow = neg ? ((k + s) & 255) : k;
    float wi = wl[(size_t)((2*si)*256 + krow)*256 + j];
    float ww = wl[(size_t)((2*si+1)*256 + krow)*256 + j];
    v = neg ? (wi - ww) : (wi + ww);
  } else {
    v = -2.f * wg[(size_t)((sg-8)*2*256 + k)*256 + j];
  }
  WT[idx] = f2h(v);
}

// W_eff (fp16) in layout [b][8 k32][4 q][256 n=j][8 e]
__global__ __launch_bounds__(256) void k_prep_weff(const float* __restrict__ wg,
                                                   const float* __restrict__ m,
                                                   unsigned short* __restrict__ WT){
  int b = blockIdx.x >> 8, c = blockIdx.x & 255, j = threadIdx.x;
  float acc = 0.f;
  #pragma unroll
  for (int si=0; si<2; ++si){
    int s = si+1;
    int cm = (c - s) & 255, cp = (c + s) & 255;
    float wi_c  = wg[(size_t)((2*si)*256 + c)*256 + j];
    float ww_c  = wg[(size_t)((2*si+1)*256 + c)*256 + j];
    float wi_cp = wg[(size_t)((2*si)*256 + cp)*256 + j];
    float ww_cp = wg[(size_t)((2*si+1)*256 + cp)*256 + j];
    acc += m[b*256+cm]*(wi_c+ww_c) + m[b*256+cp]*(wi_cp-ww_cp);
  }
  size_t addr = (size_t)b*65536 + (size_t)(c>>5)*8192 + (size_t)((c>>3)&3)*2048
              + (size_t)j*8 + (c&7);
  WT[addr] = f2h(acc);
}

// ---------------- fused depthwise 3x3 + 3x3 + BN + SiLU - z_det
__global__ __launch_bounds__(256) void k_dwf(const unsigned short* __restrict__ A3,
                                             const float* __restrict__ w1g,
                                             const float* __restrict__ w2g,
                                             const float* __restrict__ bg,
                                             const float* __restrict__ bm_,
                                             const float* __restrict__ bv,
                                             const unsigned short* __restrict__ zdet,
                                             unsigned short* __restrict__ zcx){
  __shared__ unsigned short t0[12800];   // [20][20][32] bf16
  __shared__ unsigned short t1[10368];   // [18][18][32] fp16
  int t = blockIdx.x;
  int img = t >> 6, ty = (t>>3)&7, tx = t&7;
  int c0 = blockIdx.y*32;
  int tid = threadIdx.x;
  int ch = tid & 31;
  int c = c0 + ch;
  for (int v = tid; v < 3200; v += 256){
    int py = v / 160, rem = v - py*160;
    int px = rem >> 3, ch4 = (rem & 7)*4;
    int gpy = ty*16 - 2 + py, gpx = tx*16 - 2 + px;
    ushort4v val = {0,0,0,0};
    if ((unsigned)gpy < 128u && (unsigned)gpx < 128u){
      size_t gp = (size_t)(img*16384 + gpy*128 + gpx);
      val = *(const ushort4v*)&A3[gp*512 + c0 + ch4];
    }
    *(ushort4v*)&t0[(py*20+px)*32 + ch4] = val;
  }
  float w1[9], w2[9];
  #pragma unroll
  for (int k=0;k<9;k++){ w1[k] = w1g[k*256 + c]; w2[k] = w2g[k*256 + c]; }
  __syncthreads();
  for (int p = tid>>5; p < 324; p += 8){
    int py = p / 18, px = p - py*18;
    int gpy = ty*16 - 1 + py, gpx = tx*16 - 1 + px;
    float acc = 0.f;
    #pragma unroll
    for (int dy=0; dy<3; ++dy)
      #pragma unroll
      for (int dx=0; dx<3; ++dx)
        acc += bf2f(t0[((py+dy)*20 + px+dx)*32 + ch]) * w1[dy*3+dx];
    bool valid = ((unsigned)gpy < 128u) && ((unsigned)gpx < 128u);
    t1[p*32 + ch] = valid ? f2h(acc) : (unsigned short)0;
  }
  __syncthreads();
  float bmv = bm_[c];
  float rsbg = rsqrtf(bv[c] + 1e-3f) * bg[c];
  for (int p = tid>>5; p < 256; p += 8){
    int py = p >> 4, px = p & 15;
    float acc = 0.f;
    #pragma unroll
    for (int dy=0; dy<3; ++dy)
      #pragma unroll
      for (int dx=0; dx<3; ++dx)
        acc += h2f(t1[((py+dy)*18 + px+dx)*32 + ch]) * w2[dy*3+dx];
    float tv = (acc - bmv) * rsbg;
    float sv = tv / (1.f + __expf(-tv));
    size_t gp = (size_t)(img*16384 + (ty*16+py)*128 + tx*16+px);
    float z = sv - h2f(zdet[gp*256 + c]);
    zcx[gp*256 + c] = f2h(z);
  }
}

// ---------------- generic MFMA GEMM: C = A[M,K] * (Bt[N,K])^T, 128x128 tile, BK=64
template<int EPI>
__global__ __launch_bounds__(256) void k_gemm(const unsigned short* __restrict__ A, int lda,
                                              const unsigned short* __restrict__ Bt, int K,
                                              unsigned short* __restrict__ outh,
                                              const float* __restrict__ xin,
                                              const unsigned short* __restrict__ A3,
                                              const float* __restrict__ gls,
                                              float* __restrict__ out){
  __shared__ unsigned short As[128*64];
  __shared__ unsigned short Bs[128*64];
  const int tid=threadIdx.x, lane=tid&63, wid=tid>>6;
  const int bm = blockIdx.x*128, bn = blockIdx.y*128;
  const int wr = wid>>1, wc = wid&1;
  f32x4 acc[4][4] = {};
  const int nk = K>>6;
  const int srow = lane>>3;
  const int skc  = ((lane&7) ^ srow) * 8;
  for (int t=0; t<nk; ++t){
    int k0 = t*64;
    #pragma unroll
    for (int i=0;i<4;i++){
      int q = wid*4 + i;
      int row = q*8 + srow;
      gll16(A  + (size_t)(bm+row)*lda + k0 + skc, &As[q*512]);
      gll16(Bt + (size_t)(bn+row)*K   + k0 + skc, &Bs[q*512]);
    }
    __syncthreads();
    #pragma unroll
    for (int kk=0; kk<2; ++kk){
      bf16x8 af[4], bfr[4];
      #pragma unroll
      for (int i=0;i<4;i++){
        int rl = wr*64 + i*16 + (lane&15);
        int kc = (kk*32 + (lane>>4)*8) ^ ((rl&7)*8);
        af[i]  = *(const bf16x8*)&As[rl*64 + kc];
        int cl = wc*64 + i*16 + (lane&15);
        int kcb = (kk*32 + (lane>>4)*8) ^ ((cl&7)*8);
        bfr[i] = *(const bf16x8*)&Bs[cl*64 + kcb];
      }
      #pragma unroll
      for (int i=0;i<4;i++)
        #pragma unroll
        for (int j=0;j<4;j++)
          acc[i][j] = __builtin_amdgcn_mfma_f32_16x16x32_bf16(af[i], bfr[j], acc[i][j], 0,0,0);
    }
    __syncthreads();
  }
  #pragma unroll
  for (int i=0;i<4;i++)
    #pragma unroll
    for (int j=0;j<4;j++)
      #pragma unroll
      for (int r=0;r<4;r++){
        int row = bm + wr*64 + i*16 + (lane>>4)*4 + r;
        int col = bn + wc*64 + j*16 + (lane&15);
        float v = acc[i][j][r];
        if constexpr (EPI==0){
          outh[(size_t)row*256 + col] = f2h(v);   // z_det in FP16
        } else {
          float alpha = 1.f/(1.f+__expf(-v));
          float xnv = bf2f(A3[(size_t)row*512 + col]);
          float gfv = bf2f(A3[(size_t)row*512 + 256 + col]);
          float sl = xnv/(1.f+__expf(-xnv));
          out[(size_t)row*256 + col] = xin[(size_t)row*256 + col] + (sl + alpha*gfv)*gls[col];
        }
      }
}

// ---------------- fused geo GEMM (R7 structure) with ABLATION variants.
// ABL=0 real; ABL=1 MFMA-only (no mem, no sync); ABL=2 panel path only
// (staging+barriers+LDS reads, const operands); ABL=3 operand path only
// (global operand loads + af-gen, const B, barriers kept).
template<int S>
__device__ __attribute__((always_inline)) ushort8 shsel(ushort8 hi, ushort8 lo){
  ushort8 r;
  if constexpr (S==0) return hi;
  #pragma unroll
  for (int e=0;e<8;e++) r[e] = (e<S) ? lo[8-S+e] : hi[e-S];
  return r;
}

template<int SEG>
__device__ __attribute__((always_inline)) f16x8 gen2(ushort8 zdh, ushort8 zdl,
      ushort8 zch, ushort8 zcl, ushort8 zcu){
  if constexpr (SEG==10) return __builtin_bit_cast(f16x8, zdh);
  ushort8 sel;
  if constexpr      (SEG==0) sel = shsel<1>(zch, zcl);
  else if constexpr (SEG==1) sel = shsel<7>(zcu, zch);
  else if constexpr (SEG==2) sel = shsel<2>(zch, zcl);
  else if constexpr (SEG==3) sel = shsel<6>(zcu, zch);
  else if constexpr (SEG==4) sel = shsel<4>(zch, zcl);
  else if constexpr (SEG==5) sel = shsel<4>(zcu, zch);
  else if constexpr (SEG==6) sel = zcl;
  else if constexpr (SEG==7) sel = zcu;
  else if constexpr (SEG==8) sel = shsel<1>(zdh, zdl);
  else                       sel = shsel<2>(zdh, zdl);
  return __builtin_bit_cast(f16x8, zdh) * __builtin_bit_cast(f16x8, sel);
}

template<int ABL>
__global__ __launch_bounds__(512, 2) void k_geo(const unsigned short* __restrict__ zd,
                                                const unsigned short* __restrict__ zc,
                                                const unsigned short* __restrict__ WT_all,
                                                const unsigned short* __restrict__ WeffT,
                                                unsigned short* __restrict__ A3,
                                                float* __restrict__ dbg){
  constexpr bool PANEL = (ABL==0 || ABL==2);
  constexpr bool OPER  = (ABL==0 || ABL==3);
  constexpr bool SYNC  = (ABL!=1);
  __shared__ unsigned short Bs[4][8192];     // ring-4 x 16KB panels [q][n][8]
  const int tid = threadIdx.x, lane = tid&63, wid = tid>>6;
  const int bm = blockIdx.x*128;
  const int img = blockIdx.x >> 7;
  const unsigned short* weff = WeffT + (size_t)img*65536;
  const int rh = wid >> 2, cq = wid & 3;     // wave tile: 64 rows x 64 cols
  f32x4 acc[4][4] = {};
  const int boff = (lane>>4)*2048 + (cq*64 + (lane&15))*8;   // halfs

  const int mrow = bm + rh*64 + (lane&15);
  const unsigned short* zrow[4];
  const unsigned short* crow[4];
  #pragma unroll
  for (int rg=0; rg<4; ++rg){
    zrow[rg] = zd + (size_t)(mrow + rg*16)*256;
    crow[rg] = zc + (size_t)(mrow + rg*16)*256;
  }

  ushort8 zdh[4], zdl[4], zch[4], zcl[4], zcu[4];
  ushort8 cst;
  #pragma unroll
  for (int e=0;e<8;e++) cst[e] = (unsigned short)(0x3800 + lane + e);  // ~0.5 fp16

  // prologue
  if constexpr (PANEL){
    if (wid < 3){
      const unsigned short* src = WT_all + (size_t)wid*65536 + lane*8;
      unsigned short* dst = &Bs[wid][0];
      #pragma unroll
      for (int gq=0; gq<16; ++gq) gll16(src + gq*512, dst + gq*512);
      asm volatile("s_waitcnt vmcnt(0)" ::: "memory");
    }
  }
  if constexpr (OPER){
    int kc = (lane>>4)*8, kl = (kc-8)&255, ku = (kc+8)&255;
    #pragma unroll
    for (int rg=0; rg<4; ++rg){
      zdh[rg] = *(const ushort8*)(zrow[rg] + kc);
      zdl[rg] = *(const ushort8*)(zrow[rg] + kl);
      zch[rg] = *(const ushort8*)(crow[rg] + kc);
      zcl[rg] = *(const ushort8*)(crow[rg] + kl);
      zcu[rg] = *(const ushort8*)(crow[rg] + ku);
    }
  } else {
    #pragma unroll
    for (int rg=0; rg<4; ++rg){ zdh[rg]=cst; zdl[rg]=cst; zch[rg]=cst; zcl[rg]=cst; zcu[rg]=cst; }
  }
  if constexpr (SYNC) __builtin_amdgcn_s_barrier();

  int t = 0, cur = 0;

#define CSTEP(SEG) { \
    if constexpr (PANEL){ \
      if (((t & 7) == wid) && (t+3) < 88){ \
        int st = t + 3; \
        int k32s = (st*373) >> 12; \
        int segs = st - k32s*11; \
        const unsigned short* src = ((segs<10) ? (WT_all + (size_t)segs*65536) : weff) \
                                    + (size_t)k32s*8192 + lane*8; \
        unsigned short* dst = &Bs[st & 3][0]; \
        _Pragma("unroll") \
        for (int gq=0; gq<16; ++gq) gll16(src + gq*512, dst + gq*512); \
      } \
    } \
    f16x8 bfr[4]; \
    if constexpr (PANEL){ \
      const unsigned short* bp = &Bs[0][0] + cur*8192 + boff; \
      bfr[0] = *(const f16x8*)(bp); \
      bfr[1] = *(const f16x8*)(bp + 128); \
      bfr[2] = *(const f16x8*)(bp + 256); \
      bfr[3] = *(const f16x8*)(bp + 384); \
    } else { \
      bfr[0] = __builtin_bit_cast(f16x8, cst); bfr[1] = bfr[0]; \
      bfr[2] = bfr[0]; bfr[3] = bfr[0]; \
    } \
    if constexpr (OPER){ \
      if constexpr ((SEG)==8){ \
        int k32n = (k32<7) ? k32+1 : 7; \
        int kc_ = k32n*32 + (lane>>4)*8; \
        int kl_ = (kc_-8)&255, ku_ = (kc_+8)&255; \
        _Pragma("unroll") \
        for (int rg=0; rg<4; ++rg){ \
          zch[rg] = *(const ushort8*)(crow[rg] + kc_); \
          zcl[rg] = *(const ushort8*)(crow[rg] + kl_); \
          zcu[rg] = *(const ushort8*)(crow[rg] + ku_); \
        } \
      } \
    } \
    f16x8 af[4]; \
    if constexpr (OPER){ \
      _Pragma("unroll") \
      for (int rg=0; rg<4; ++rg) \
        af[rg] = gen2<(SEG)>(zdh[rg],zdl[rg],zch[rg],zcl[rg],zcu[rg]); \
    } else { \
      af[0] = __builtin_bit_cast(f16x8, cst); af[1] = af[0]; af[2] = af[0]; af[3] = af[0]; \
    } \
    if constexpr (OPER){ \
      if constexpr ((SEG)==10){ \
        int k32n = (k32<7) ? k32+1 : 7; \
        int kc_ = k32n*32 + (lane>>4)*8; \
        int kl_ = (kc_-8)&255; \
        _Pragma("unroll") \
        for (int rg=0; rg<4; ++rg){ \
          zdh[rg] = *(const ushort8*)(zrow[rg] + kc_); \
          zdl[rg] = *(const ushort8*)(zrow[rg] + kl_); \
        } \
      } \
    } \
    __builtin_amdgcn_s_setprio(1); \
    _Pragma("unroll") \
    for (int fj=0; fj<4; ++fj){ \
      _Pragma("unroll") \
      for (int rg=0; rg<4; ++rg) \
        acc[rg][fj] = __builtin_amdgcn_mfma_f32_16x16x32_f16(af[rg], bfr[fj], acc[rg][fj], 0,0,0); \
    } \
    __builtin_amdgcn_s_setprio(0); \
    if constexpr (SYNC){ \
      asm volatile("s_waitcnt vmcnt(10)" ::: "memory"); \
      __builtin_amdgcn_s_barrier(); \
    } \
    cur = (cur+1) & 3; \
    ++t; \
  }

  for (int k32=0; k32<8; ++k32){
    CSTEP(0) CSTEP(1) CSTEP(2) CSTEP(3) CSTEP(4) CSTEP(5)
    CSTEP(6) CSTEP(7) CSTEP(8) CSTEP(9) CSTEP(10)
  }
#undef CSTEP

  if constexpr (ABL != 0){
    float s = 0.f;
    #pragma unroll
    for (int rg=0; rg<4; ++rg)
      #pragma unroll
      for (int fj=0; fj<4; ++fj)
        #pragma unroll
        for (int r=0; r<4; ++r) s += acc[rg][fj][r];
    dbg[blockIdx.x*512 + tid] = s;
    return;
  }

  #pragma unroll
  for (int rg=0; rg<4; ++rg)
    #pragma unroll
    for (int fj=0; fj<4; ++fj)
      #pragma unroll
      for (int r=0; r<4; ++r){
        int row = bm + rh*64 + rg*16 + (lane>>4)*4 + r;
        int col = cq*64 + fj*16 + (lane&15);
        A3[(size_t)row*512 + 256 + col] = f2bf(acc[rg][fj][r]);
      }
}

extern "C" void kernel_launch(void* const* d_in, const int* in_sizes, int n_in,
                              void* d_out, int out_size, void* d_ws, size_t ws_size,
                              hipStream_t stream){
  (void)in_sizes; (void)n_in; (void)out_size; (void)ws_size;
  const float* x    = (const float*)d_in[0];
  const float* lng  = (const float*)d_in[1];
  const float* wdet = (const float*)d_in[2];
  const float* dw1  = (const float*)d_in[3];
  const float* dw2  = (const float*)d_in[4];
  const float* bng  = (const float*)d_in[5];
  const float* bnm  = (const float*)d_in[6];
  const float* bnv  = (const float*)d_in[7];
  const float* wloc = (const float*)d_in[8];
  const float* wglo = (const float*)d_in[9];
  const float* wgat = (const float*)d_in[10];
  const float* gls  = (const float*)d_in[11];
  float* out = (float*)d_out;
  char* ws = (char*)d_ws;

  unsigned short* A3     = (unsigned short*)(ws);                 // 64 MB [65536][512] bf16
  unsigned short* ZDET   = (unsigned short*)(ws + 67108864);      // 32 MB fp16
  float*          DBG    = (float*)(ws + 100663296);              // 3 MB ablation scratch
  unsigned short* ZCX    = (unsigned short*)(ws + 134217728);     // 32 MB fp16
  unsigned short* WTALL  = (unsigned short*)(ws + 167772160);     // 1.25 MB fp16 [10][8][4][256][8]
  unsigned short* WEFFT  = (unsigned short*)(ws + 169213952);     // 0.5 MB fp16 [4][8][4][256][8]
  unsigned short* WDETT  = (unsigned short*)(ws + 169738240);     // 128 KB bf16
  unsigned short* WGATET = (unsigned short*)(ws + 169869312);     // 256 KB bf16
  float* PSUM  = (float*)(ws + 170131456);                        // 256 KB
  float* MMEAN = (float*)(ws + 170393600);                        // 4 KB

  k_ln<<<16384, 256, 0, stream>>>(x, lng, A3);
  k_cm1<<<256, 256, 0, stream>>>(A3, PSUM);
  k_cm2<<<4, 256, 0, stream>>>(PSUM, MMEAN);
  k_prep_nt<<<256, 256, 0, stream>>>(wdet, WDETT, 256);
  k_prep_nt<<<512, 256, 0, stream>>>(wgat, WGATET, 512);
  k_prep_geoT<<<2560, 256, 0, stream>>>(wloc, wglo, WTALL);
  k_prep_weff<<<1024, 256, 0, stream>>>(wglo, MMEAN, WEFFT);
  k_gemm<0><<<dim3(512,2), 256, 0, stream>>>(A3, 512, WDETT, 256, ZDET,
                                             nullptr, nullptr, nullptr, nullptr);
  k_dwf<<<dim3(256,8), 256, 0, stream>>>(A3, dw1, dw2, bng, bnm, bnv, ZDET, ZCX);
  // ---- ablation dispatches (diagnostic; outputs dead scratch) ----
  k_geo<1><<<512, 512, 0, stream>>>(ZDET, ZCX, WTALL, WEFFT, A3, DBG);
  k_geo<2><<<512, 512, 0, stream>>>(ZDET, ZCX, WTALL, WEFFT, A3, DBG + 262144);
  k_geo<3><<<512, 512, 0, stream>>>(ZDET, ZCX, WTALL, WEFFT, A3, DBG + 524288);
  // ---- real ----
  k_geo<0><<<512, 512, 0, stream>>>(ZDET, ZCX, WTALL, WEFFT, A3, nullptr);
  k_gemm<1><<<dim3(512,2), 256, 0, stream>>>(A3, 512, WGATET, 512, nullptr,
                                             x, A3, gls, out);
}

// Round 10
// 377.954 us; speedup vs baseline: 1.4824x; 1.4824x over previous
//
#include <hip/hip_runtime.h>

typedef __attribute__((ext_vector_type(8))) short bf16x8;
typedef __attribute__((ext_vector_type(8))) unsigned short ushort8;
typedef __attribute__((ext_vector_type(4))) unsigned short ushort4v;
typedef __attribute__((ext_vector_type(4))) float f32x4;
typedef __attribute__((ext_vector_type(4))) float float4v;
typedef __attribute__((ext_vector_type(8))) _Float16 f16x8;

__device__ inline unsigned short f2bf(float f){
  unsigned u = __builtin_bit_cast(unsigned, f);
  return (unsigned short)((u + 0x7fffu + ((u>>16)&1u)) >> 16);
}
__device__ inline float bf2f(unsigned short h){
  return __builtin_bit_cast(float, (unsigned)h << 16);
}
__device__ inline unsigned short f2h(float f){
  return __builtin_bit_cast(unsigned short, (_Float16)f);
}
__device__ inline float h2f(unsigned short u){
  return (float)__builtin_bit_cast(_Float16, u);
}

__device__ inline void gll16(const void* g, void* l){
  __builtin_amdgcn_global_load_lds((const __attribute__((address_space(1))) void*)g,
                                   (__attribute__((address_space(3))) void*)l, 16, 0, 0);
}

// ---------------- LayerNorm: one wave per row, float4 loads
__global__ __launch_bounds__(256) void k_ln(const float* __restrict__ x,
                                            const float* __restrict__ g,
                                            unsigned short* __restrict__ A3){
  int wid = threadIdx.x >> 6, lane = threadIdx.x & 63;
  int row = blockIdx.x*4 + wid;
  float4v v = *(const float4v*)&x[(size_t)row*256 + lane*4];
  float4v gv = *(const float4v*)&g[lane*4];
  float s  = v[0]+v[1]+v[2]+v[3];
  float s2 = v[0]*v[0]+v[1]*v[1]+v[2]*v[2]+v[3]*v[3];
  #pragma unroll
  for (int m=32; m>=1; m>>=1){ s += __shfl_xor(s, m, 64); s2 += __shfl_xor(s2, m, 64); }
  float mu  = s*(1.f/256.f);
  float var = s2*(1.f/256.f) - mu*mu;
  float rst = rsqrtf(var + 1e-6f);
  ushort4v o;
  #pragma unroll
  for (int e=0;e<4;e++) o[e] = f2bf((v[e]-mu)*rst*gv[e]);
  *(ushort4v*)&A3[(size_t)row*512 + lane*4] = o;
}

// ---------------- column means of x_norm per image
__global__ __launch_bounds__(256) void k_cm1(const unsigned short* __restrict__ A3,
                                             float* __restrict__ psum){
  int blk = blockIdx.x;
  int c = threadIdx.x;
  const unsigned short* base = A3 + (size_t)blk*256*512;
  float s = 0.f;
  for (int p=0;p<256;p++) s += bf2f(base[(size_t)p*512 + c]);
  psum[blk*256 + c] = s;
}
__global__ __launch_bounds__(256) void k_cm2(const float* __restrict__ psum,
                                             float* __restrict__ m){
  int b = blockIdx.x, c = threadIdx.x;
  float s = 0.f;
  for (int ch=0; ch<64; ch++) s += psum[(b*64+ch)*256 + c];
  m[b*256 + c] = s*(1.f/16384.f);
}

// ---------------- weight transposes to bf16 (Bt layout [N][K]) for the two GEMMs
__global__ __launch_bounds__(256) void k_prep_nt(const float* __restrict__ W,
                                                 unsigned short* __restrict__ WT, int K){
  int idx = blockIdx.x*256 + threadIdx.x;
  int j = idx / K, k = idx - j*K;
  WT[idx] = f2bf(W[(size_t)k*256 + j]);
}

// geo weights -> FP16 panels [10][8 k32][2 cb][4 q][128 n][8 e]
// element: k = k32*32+q*8+e, j = cb*128+n
__global__ __launch_bounds__(256) void k_prep_geoT(const float* __restrict__ wl,
                                                   const float* __restrict__ wg,
                                                   unsigned short* __restrict__ WT){
  int idx = blockIdx.x*256 + threadIdx.x;     // over 10*65536, output-linear
  int e = idx & 7, n = (idx>>3)&127, q = (idx>>10)&3, cb = (idx>>12)&1,
      k32 = (idx>>13)&7, sg = idx>>16;
  int k = k32*32 + q*8 + e;
  int j = cb*128 + n;
  float v;
  if (sg < 8){
    int si = sg >> 1, s = 1 << si;
    bool neg = sg & 1;
    int krow = neg ? ((k + s) & 255) : k;
    float wi = wl[(size_t)((2*si)*256 + krow)*256 + j];
    float ww = wl[(size_t)((2*si+1)*256 + krow)*256 + j];
    v = neg ? (wi - ww) : (wi + ww);
  } else {
    v = -2.f * wg[(size_t)((sg-8)*2*256 + k)*256 + j];
  }
  WT[idx] = f2h(v);
}

// W_eff (fp16) panels [b][8 k32][2 cb][4 q][128 n][8 e]; k-dim = channel c
__global__ __launch_bounds__(256) void k_prep_weff(const float* __restrict__ wg,
                                                   const float* __restrict__ m,
                                                   unsigned short* __restrict__ WT){
  int b = blockIdx.x >> 8, c = blockIdx.x & 255, j = threadIdx.x;
  float acc = 0.f;
  #pragma unroll
  for (int si=0; si<2; ++si){
    int s = si+1;
    int cm = (c - s) & 255, cp = (c + s) & 255;
    float wi_c  = wg[(size_t)((2*si)*256 + c)*256 + j];
    float ww_c  = wg[(size_t)((2*si+1)*256 + c)*256 + j];
    float wi_cp = wg[(size_t)((2*si)*256 + cp)*256 + j];
    float ww_cp = wg[(size_t)((2*si+1)*256 + cp)*256 + j];
    acc += m[b*256+cm]*(wi_c+ww_c) + m[b*256+cp]*(wi_cp-ww_cp);
  }
  size_t addr = (size_t)b*65536 + (size_t)(c>>5)*8192 + (size_t)(j>>7)*4096
              + (size_t)((c>>3)&3)*1024 + (size_t)(j&127)*8 + (c&7);
  WT[addr] = f2h(acc);
}

// ---------------- fused depthwise 3x3 + 3x3 + BN + SiLU - z_det
__global__ __launch_bounds__(256) void k_dwf(const unsigned short* __restrict__ A3,
                                             const float* __restrict__ w1g,
                                             const float* __restrict__ w2g,
                                             const float* __restrict__ bg,
                                             const float* __restrict__ bm_,
                                             const float* __restrict__ bv,
                                             const unsigned short* __restrict__ zdet,
                                             unsigned short* __restrict__ zcx){
  __shared__ unsigned short t0[12800];   // [20][20][32] bf16
  __shared__ unsigned short t1[10368];   // [18][18][32] fp16
  int t = blockIdx.x;
  int img = t >> 6, ty = (t>>3)&7, tx = t&7;
  int c0 = blockIdx.y*32;
  int tid = threadIdx.x;
  int ch = tid & 31;
  int c = c0 + ch;
  for (int v = tid; v < 3200; v += 256){
    int py = v / 160, rem = v - py*160;
    int px = rem >> 3, ch4 = (rem & 7)*4;
    int gpy = ty*16 - 2 + py, gpx = tx*16 - 2 + px;
    ushort4v val = {0,0,0,0};
    if ((unsigned)gpy < 128u && (unsigned)gpx < 128u){
      size_t gp = (size_t)(img*16384 + gpy*128 + gpx);
      val = *(const ushort4v*)&A3[gp*512 + c0 + ch4];
    }
    *(ushort4v*)&t0[(py*20+px)*32 + ch4] = val;
  }
  float w1[9], w2[9];
  #pragma unroll
  for (int k=0;k<9;k++){ w1[k] = w1g[k*256 + c]; w2[k] = w2g[k*256 + c]; }
  __syncthreads();
  for (int p = tid>>5; p < 324; p += 8){
    int py = p / 18, px = p - py*18;
    int gpy = ty*16 - 1 + py, gpx = tx*16 - 1 + px;
    float acc = 0.f;
    #pragma unroll
    for (int dy=0; dy<3; ++dy)
      #pragma unroll
      for (int dx=0; dx<3; ++dx)
        acc += bf2f(t0[((py+dy)*20 + px+dx)*32 + ch]) * w1[dy*3+dx];
    bool valid = ((unsigned)gpy < 128u) && ((unsigned)gpx < 128u);
    t1[p*32 + ch] = valid ? f2h(acc) : (unsigned short)0;
  }
  __syncthreads();
  float bmv = bm_[c];
  float rsbg = rsqrtf(bv[c] + 1e-3f) * bg[c];
  for (int p = tid>>5; p < 256; p += 8){
    int py = p >> 4, px = p & 15;
    float acc = 0.f;
    #pragma unroll
    for (int dy=0; dy<3; ++dy)
      #pragma unroll
      for (int dx=0; dx<3; ++dx)
        acc += h2f(t1[((py+dy)*18 + px+dx)*32 + ch]) * w2[dy*3+dx];
    float tv = (acc - bmv) * rsbg;
    float sv = tv / (1.f + __expf(-tv));
    size_t gp = (size_t)(img*16384 + (ty*16+py)*128 + tx*16+px);
    float z = sv - h2f(zdet[gp*256 + c]);
    zcx[gp*256 + c] = f2h(z);
  }
}

// ---------------- generic MFMA GEMM: C = A[M,K] * (Bt[N,K])^T, 128x128 tile, BK=64
template<int EPI>
__global__ __launch_bounds__(256) void k_gemm(const unsigned short* __restrict__ A, int lda,
                                              const unsigned short* __restrict__ Bt, int K,
                                              unsigned short* __restrict__ outh,
                                              const float* __restrict__ xin,
                                              const unsigned short* __restrict__ A3,
                                              const float* __restrict__ gls,
                                              float* __restrict__ out){
  __shared__ unsigned short As[128*64];
  __shared__ unsigned short Bs[128*64];
  const int tid=threadIdx.x, lane=tid&63, wid=tid>>6;
  const int bm = blockIdx.x*128, bn = blockIdx.y*128;
  const int wr = wid>>1, wc = wid&1;
  f32x4 acc[4][4] = {};
  const int nk = K>>6;
  const int srow = lane>>3;
  const int skc  = ((lane&7) ^ srow) * 8;
  for (int t=0; t<nk; ++t){
    int k0 = t*64;
    #pragma unroll
    for (int i=0;i<4;i++){
      int q = wid*4 + i;
      int row = q*8 + srow;
      gll16(A  + (size_t)(bm+row)*lda + k0 + skc, &As[q*512]);
      gll16(Bt + (size_t)(bn+row)*K   + k0 + skc, &Bs[q*512]);
    }
    __syncthreads();
    #pragma unroll
    for (int kk=0; kk<2; ++kk){
      bf16x8 af[4], bfr[4];
      #pragma unroll
      for (int i=0;i<4;i++){
        int rl = wr*64 + i*16 + (lane&15);
        int kc = (kk*32 + (lane>>4)*8) ^ ((rl&7)*8);
        af[i]  = *(const bf16x8*)&As[rl*64 + kc];
        int cl = wc*64 + i*16 + (lane&15);
        int kcb = (kk*32 + (lane>>4)*8) ^ ((cl&7)*8);
        bfr[i] = *(const bf16x8*)&Bs[cl*64 + kcb];
      }
      #pragma unroll
      for (int i=0;i<4;i++)
        #pragma unroll
        for (int j=0;j<4;j++)
          acc[i][j] = __builtin_amdgcn_mfma_f32_16x16x32_bf16(af[i], bfr[j], acc[i][j], 0,0,0);
    }
    __syncthreads();
  }
  #pragma unroll
  for (int i=0;i<4;i++)
    #pragma unroll
    for (int j=0;j<4;j++)
      #pragma unroll
      for (int r=0;r<4;r++){
        int row = bm + wr*64 + i*16 + (lane>>4)*4 + r;
        int col = bn + wc*64 + j*16 + (lane&15);
        float v = acc[i][j][r];
        if constexpr (EPI==0){
          outh[(size_t)row*256 + col] = f2h(v);   // z_det in FP16
        } else {
          float alpha = 1.f/(1.f+__expf(-v));
          float xnv = bf2f(A3[(size_t)row*512 + col]);
          float gfv = bf2f(A3[(size_t)row*512 + 256 + col]);
          float sl = xnv/(1.f+__expf(-xnv));
          out[(size_t)row*256 + col] = xin[(size_t)row*256 + col] + (sl + alpha*gfv)*gls[col];
        }
      }
}

// ---------------- fused geo GEMM v10: 64-MFMA periods, 24 barriers total.
// grid 512 = 256 row-blocks x 2 col-halves (XCD-swizzled). Block 1024 thr =
// 16 waves (8 row x 2 col), wave tile 32r x 64c, acc 32 f32 (<=128 VGPR ->
// 2 blocks/CU, 8 waves/SIMD). Per k32: 11 panels (N=128 fp16, 8KB) in 3
// groups {0-3},{4-7},{8,9,Weff} through 2x32KB LDS dbuf; per period each
// wave issues 2 gll16 (next group) then 4segs x 8 MFMA; vmcnt+barrier.
template<int S>
__device__ __attribute__((always_inline)) ushort8 shsel(ushort8 hi, ushort8 lo){
  ushort8 r;
  if constexpr (S==0) return hi;
  #pragma unroll
  for (int e=0;e<8;e++) r[e] = (e<S) ? lo[8-S+e] : hi[e-S];
  return r;
}

template<int SEG>
__device__ __attribute__((always_inline)) f16x8 gen2(ushort8 zdh, ushort8 zdl,
      ushort8 zch, ushort8 zcl, ushort8 zcu){
  if constexpr (SEG==10) return __builtin_bit_cast(f16x8, zdh);
  ushort8 sel;
  if constexpr      (SEG==0) sel = shsel<1>(zch, zcl);
  else if constexpr (SEG==1) sel = shsel<7>(zcu, zch);
  else if constexpr (SEG==2) sel = shsel<2>(zch, zcl);
  else if constexpr (SEG==3) sel = shsel<6>(zcu, zch);
  else if constexpr (SEG==4) sel = shsel<4>(zch, zcl);
  else if constexpr (SEG==5) sel = shsel<4>(zcu, zch);
  else if constexpr (SEG==6) sel = zcl;
  else if constexpr (SEG==7) sel = zcu;
  else if constexpr (SEG==8) sel = shsel<1>(zdh, zdl);
  else                       sel = shsel<2>(zdh, zdl);
  return __builtin_bit_cast(f16x8, zdh) * __builtin_bit_cast(f16x8, sel);
}

__global__ __launch_bounds__(1024, 4) void k_geo(const unsigned short* __restrict__ zd,
                                                 const unsigned short* __restrict__ zc,
                                                 const unsigned short* __restrict__ WT_all,
                                                 const unsigned short* __restrict__ WeffT,
                                                 unsigned short* __restrict__ A3){
  __shared__ unsigned short Bs[2][16384];    // 2 x 32KB group buffers
  const int tid = threadIdx.x, lane = tid&63, wid = tid>>6;   // wid 0..15
  const int bx = blockIdx.x;
  const int swz = (bx & 7)*64 + (bx >> 3);   // bijective XCD swizzle (512%8==0)
  const int rb = swz >> 1, cb = swz & 1;
  const int img = rb >> 6;
  const unsigned short* weff = WeffT + (size_t)img*65536;
  const int wrow = wid >> 1, wcol = wid & 1;
  f32x4 acc[2][4] = {};

  const int mrow0 = rb*256 + wrow*32 + (lane&15);
  const unsigned short* zrow[2];
  const unsigned short* crow[2];
  #pragma unroll
  for (int rg=0; rg<2; ++rg){
    zrow[rg] = zd + (size_t)(mrow0 + rg*16)*256;
    crow[rg] = zc + (size_t)(mrow0 + rg*16)*256;
  }
  // frag read base (halfs, within a buffer): + p*4096 + fj*128
  const int fbase = (lane>>4)*1024 + wcol*512 + (lane&15)*8;

  ushort8 zdh[2], zdl[2], zch[2], zcl[2], zcu[2];

#define LOADOPS(K32n) { \
    int kc_ = (K32n)*32 + (lane>>4)*8; \
    int kl_ = (kc_-8)&255, ku_ = (kc_+8)&255; \
    _Pragma("unroll") \
    for (int rg=0; rg<2; ++rg){ \
      zdh[rg] = *(const ushort8*)(zrow[rg] + kc_); \
      zdl[rg] = *(const ushort8*)(zrow[rg] + kl_); \
      zch[rg] = *(const ushort8*)(crow[rg] + kc_); \
      zcl[rg] = *(const ushort8*)(crow[rg] + kl_); \
      zcu[rg] = *(const ushort8*)(crow[rg] + ku_); \
    } }

  // stage group g (0/1): panels sg=g*4+p, 32 chunks of 1KB, 2 per wave
#define STAGE01(G, K32s, DB) { \
    _Pragma("unroll") \
    for (int c2=0; c2<2; ++c2){ \
      int ch_ = wid*2 + c2; \
      int p_ = ch_>>3, off_ = (ch_&7)*512; \
      const unsigned short* src_ = WT_all \
          + (size_t)((((G)*4 + p_)*8 + (K32s))*2 + cb)*4096 + off_ + lane*8; \
      gll16(src_, &Bs[DB][p_*4096 + off_]); \
    } }

  // stage group 2: panels {seg8, seg9, Weff}, 24 chunks
#define STAGE2(K32s, DB) { \
    if (wid < 12){ \
      _Pragma("unroll") \
      for (int c2=0; c2<2; ++c2){ \
        int ch_ = wid*2 + c2; \
        int p_ = ch_>>3, off_ = (ch_&7)*512; \
        const unsigned short* src_ = (p_<2) \
            ? (WT_all + (size_t)(((8+p_)*8 + (K32s))*2 + cb)*4096 + off_ + lane*8) \
            : (weff + (size_t)(K32s)*8192 + cb*4096 + off_ + lane*8); \
        gll16(src_, &Bs[DB][p_*4096 + off_]); \
      } } }

#define DOSEG(SEG, P, DB) { \
    f16x8 af0 = gen2<(SEG)>(zdh[0],zdl[0],zch[0],zcl[0],zcu[0]); \
    f16x8 af1 = gen2<(SEG)>(zdh[1],zdl[1],zch[1],zcl[1],zcu[1]); \
    const unsigned short* bp = &Bs[DB][(P)*4096 + fbase]; \
    _Pragma("unroll") \
    for (int fj=0; fj<4; ++fj){ \
      f16x8 bfr = *(const f16x8*)(bp + fj*128); \
      acc[0][fj] = __builtin_amdgcn_mfma_f32_16x16x32_f16(af0, bfr, acc[0][fj], 0,0,0); \
      acc[1][fj] = __builtin_amdgcn_mfma_f32_16x16x32_f16(af1, bfr, acc[1][fj], 0,0,0); \
    } }

  // prologue: operands k32=0; stage group0(k32=0) into buf0
  LOADOPS(0)
  STAGE01(0, 0, 0)
  asm volatile("s_waitcnt vmcnt(0)" ::: "memory");
  __builtin_amdgcn_s_barrier();

  int cur = 0;
  for (int k32=0; k32<8; ++k32){
    // period g0: compute segs0-3 from buf[cur]; stage group1(k32) -> cur^1
    STAGE01(1, k32, cur^1)
    __builtin_amdgcn_s_setprio(1);
    DOSEG(0,0,cur) DOSEG(1,1,cur) DOSEG(2,2,cur) DOSEG(3,3,cur)
    __builtin_amdgcn_s_setprio(0);
    asm volatile("s_waitcnt vmcnt(0)" ::: "memory");
    __builtin_amdgcn_s_barrier();
    cur ^= 1;
    // period g1: compute segs4-7; stage group2(k32) -> cur^1
    STAGE2(k32, cur^1)
    __builtin_amdgcn_s_setprio(1);
    DOSEG(4,0,cur) DOSEG(5,1,cur) DOSEG(6,2,cur) DOSEG(7,3,cur)
    __builtin_amdgcn_s_setprio(0);
    asm volatile("s_waitcnt vmcnt(0)" ::: "memory");
    __builtin_amdgcn_s_barrier();
    cur ^= 1;
    // period g2: compute segs8,9,10; stage group0(k32+1) -> cur^1; reload ops
    if (k32 < 7){ STAGE01(0, k32+1, cur^1) }
    {
      f16x8 a8[2], a9[2], a10[2];
      #pragma unroll
      for (int rg=0; rg<2; ++rg){
        a8[rg]  = gen2<8>(zdh[rg],zdl[rg],zch[rg],zcl[rg],zcu[rg]);
        a9[rg]  = gen2<9>(zdh[rg],zdl[rg],zch[rg],zcl[rg],zcu[rg]);
        a10[rg] = gen2<10>(zdh[rg],zdl[rg],zch[rg],zcl[rg],zcu[rg]);
      }
      if (k32 < 7){ LOADOPS(k32+1) }
      const unsigned short* bp = &Bs[cur][fbase];
      __builtin_amdgcn_s_setprio(1);
      #pragma unroll
      for (int fj=0; fj<4; ++fj){
        f16x8 b8 = *(const f16x8*)(bp + fj*128);
        f16x8 b9 = *(const f16x8*)(bp + 4096 + fj*128);
        f16x8 bA = *(const f16x8*)(bp + 8192 + fj*128);
        #pragma unroll
        for (int rg=0; rg<2; ++rg){
          acc[rg][fj] = __builtin_amdgcn_mfma_f32_16x16x32_f16(a8[rg],  b8, acc[rg][fj], 0,0,0);
          acc[rg][fj] = __builtin_amdgcn_mfma_f32_16x16x32_f16(a9[rg],  b9, acc[rg][fj], 0,0,0);
          acc[rg][fj] = __builtin_amdgcn_mfma_f32_16x16x32_f16(a10[rg], bA, acc[rg][fj], 0,0,0);
        }
      }
      __builtin_amdgcn_s_setprio(0);
    }
    asm volatile("s_waitcnt vmcnt(10)" ::: "memory");
    __builtin_amdgcn_s_barrier();
    cur ^= 1;
  }
#undef DOSEG
#undef STAGE2
#undef STAGE01
#undef LOADOPS

  #pragma unroll
  for (int rg=0; rg<2; ++rg)
    #pragma unroll
    for (int fj=0; fj<4; ++fj)
      #pragma unroll
      for (int r=0; r<4; ++r){
        int row = rb*256 + wrow*32 + rg*16 + (lane>>4)*4 + r;
        int col = cb*128 + wcol*64 + fj*16 + (lane&15);
        A3[(size_t)row*512 + 256 + col] = f2bf(acc[rg][fj][r]);
      }
}

extern "C" void kernel_launch(void* const* d_in, const int* in_sizes, int n_in,
                              void* d_out, int out_size, void* d_ws, size_t ws_size,
                              hipStream_t stream){
  (void)in_sizes; (void)n_in; (void)out_size; (void)ws_size;
  const float* x    = (const float*)d_in[0];
  const float* lng  = (const float*)d_in[1];
  const float* wdet = (const float*)d_in[2];
  const float* dw1  = (const float*)d_in[3];
  const float* dw2  = (const float*)d_in[4];
  const float* bng  = (const float*)d_in[5];
  const float* bnm  = (const float*)d_in[6];
  const float* bnv  = (const float*)d_in[7];
  const float* wloc = (const float*)d_in[8];
  const float* wglo = (const float*)d_in[9];
  const float* wgat = (const float*)d_in[10];
  const float* gls  = (const float*)d_in[11];
  float* out = (float*)d_out;
  char* ws = (char*)d_ws;

  unsigned short* A3     = (unsigned short*)(ws);                 // 64 MB [65536][512] bf16
  unsigned short* ZDET   = (unsigned short*)(ws + 67108864);      // 32 MB fp16
  unsigned short* ZCX    = (unsigned short*)(ws + 134217728);     // 32 MB fp16
  unsigned short* WTALL  = (unsigned short*)(ws + 167772160);     // 1.25 MB fp16 panels
  unsigned short* WEFFT  = (unsigned short*)(ws + 169213952);     // 0.5 MB fp16 panels
  unsigned short* WDETT  = (unsigned short*)(ws + 169738240);     // 128 KB bf16
  unsigned short* WGATET = (unsigned short*)(ws + 169869312);     // 256 KB bf16
  float* PSUM  = (float*)(ws + 170131456);                        // 256 KB
  float* MMEAN = (float*)(ws + 170393600);                        // 4 KB

  k_ln<<<16384, 256, 0, stream>>>(x, lng, A3);
  k_cm1<<<256, 256, 0, stream>>>(A3, PSUM);
  k_cm2<<<4, 256, 0, stream>>>(PSUM, MMEAN);
  k_prep_nt<<<256, 256, 0, stream>>>(wdet, WDETT, 256);
  k_prep_nt<<<512, 256, 0, stream>>>(wgat, WGATET, 512);
  k_prep_geoT<<<2560, 256, 0, stream>>>(wloc, wglo, WTALL);
  k_prep_weff<<<1024, 256, 0, stream>>>(wglo, MMEAN, WEFFT);
  k_gemm<0><<<dim3(512,2), 256, 0, stream>>>(A3, 512, WDETT, 256, ZDET,
                                             nullptr, nullptr, nullptr, nullptr);
  k_dwf<<<dim3(256,8), 256, 0, stream>>>(A3, dw1, dw2, bng, bnm, bnv, ZDET, ZCX);
  k_geo<<<512, 1024, 0, stream>>>(ZDET, ZCX, WTALL, WEFFT, A3);
  k_gemm<1><<<dim3(512,2), 256, 0, stream>>>(A3, 512, WGATET, 512, nullptr,
                                             x, A3, gls, out);
}

// Round 11
// 337.687 us; speedup vs baseline: 1.6591x; 1.1192x over previous
//
#include <hip/hip_runtime.h>

typedef __attribute__((ext_vector_type(8))) short bf16x8;
typedef __attribute__((ext_vector_type(8))) unsigned short ushort8;
typedef __attribute__((ext_vector_type(4))) unsigned short ushort4v;
typedef __attribute__((ext_vector_type(4))) float f32x4;
typedef __attribute__((ext_vector_type(4))) float float4v;
typedef __attribute__((ext_vector_type(8))) _Float16 f16x8;

__device__ inline unsigned short f2bf(float f){
  unsigned u = __builtin_bit_cast(unsigned, f);
  return (unsigned short)((u + 0x7fffu + ((u>>16)&1u)) >> 16);
}
__device__ inline float bf2f(unsigned short h){
  return __builtin_bit_cast(float, (unsigned)h << 16);
}
__device__ inline unsigned short f2h(float f){
  return __builtin_bit_cast(unsigned short, (_Float16)f);
}
__device__ inline float h2f(unsigned short u){
  return (float)__builtin_bit_cast(_Float16, u);
}

__device__ inline void gll16(const void* g, void* l){
  __builtin_amdgcn_global_load_lds((const __attribute__((address_space(1))) void*)g,
                                   (__attribute__((address_space(3))) void*)l, 16, 0, 0);
}

// ---------------- LayerNorm: one wave per row, float4 loads
__global__ __launch_bounds__(256) void k_ln(const float* __restrict__ x,
                                            const float* __restrict__ g,
                                            unsigned short* __restrict__ A3){
  int wid = threadIdx.x >> 6, lane = threadIdx.x & 63;
  int row = blockIdx.x*4 + wid;
  float4v v = *(const float4v*)&x[(size_t)row*256 + lane*4];
  float4v gv = *(const float4v*)&g[lane*4];
  float s  = v[0]+v[1]+v[2]+v[3];
  float s2 = v[0]*v[0]+v[1]*v[1]+v[2]*v[2]+v[3]*v[3];
  #pragma unroll
  for (int m=32; m>=1; m>>=1){ s += __shfl_xor(s, m, 64); s2 += __shfl_xor(s2, m, 64); }
  float mu  = s*(1.f/256.f);
  float var = s2*(1.f/256.f) - mu*mu;
  float rst = rsqrtf(var + 1e-6f);
  ushort4v o;
  #pragma unroll
  for (int e=0;e<4;e++) o[e] = f2bf((v[e]-mu)*rst*gv[e]);
  *(ushort4v*)&A3[(size_t)row*512 + lane*4] = o;
}

// ---------------- column partial sums, coalesced ushort8 row-runs
__global__ __launch_bounds__(256) void k_cm1(const unsigned short* __restrict__ A3,
                                             float* __restrict__ psum){
  __shared__ float red[8][256];
  int blk = blockIdx.x, t = threadIdx.x;
  int rs = t >> 5, c8 = (t & 31)*8;
  float a[8] = {0,0,0,0,0,0,0,0};
  #pragma unroll
  for (int i=0; i<8; ++i){
    int row = blk*64 + rs + i*8;
    ushort8 v = *(const ushort8*)&A3[(size_t)row*512 + c8];
    #pragma unroll
    for (int e=0;e<8;e++) a[e] += bf2f(v[e]);
  }
  #pragma unroll
  for (int e=0;e<8;e++) red[rs][c8+e] = a[e];
  __syncthreads();
  float s = red[0][t];
  #pragma unroll
  for (int r=1;r<8;r++) s += red[r][t];
  psum[blk*256 + t] = s;
}
__global__ __launch_bounds__(256) void k_cm2(const float* __restrict__ psum,
                                             float* __restrict__ m){
  int b = blockIdx.x, c = threadIdx.x;
  float s = 0.f;
  for (int ch=0; ch<64; ch++) s += psum[(b*64+ch)*256 + c];
  m[b*256 + c] = s*(1.f/16384.f);
}

// ---------------- weight transpose to bf16 (Bt layout [N][K]), K=256 source rows
__global__ __launch_bounds__(256) void k_prep_nt(const float* __restrict__ W,
                                                 unsigned short* __restrict__ WT, int K){
  int idx = blockIdx.x*256 + threadIdx.x;
  int j = idx / K, k = idx - j*K;
  WT[idx] = f2bf(W[(size_t)k*256 + j]);
}

// geo weights -> FP16, layout [10][256 n][256 k]
__global__ __launch_bounds__(256) void k_prep_geoT(const float* __restrict__ wl,
                                                   const float* __restrict__ wg,
                                                   unsigned short* __restrict__ WT){
  int idx = blockIdx.x*256 + threadIdx.x;
  int sg = idx >> 16, rem = idx & 65535;
  int j = rem >> 8, k = rem & 255;
  float v;
  if (sg < 8){
    int si = sg >> 1, s = 1 << si;
    bool neg = sg & 1;
    int krow = neg ? ((k + s) & 255) : k;
    float wi = wl[(size_t)((2*si)*256 + krow)*256 + j];
    float ww = wl[(size_t)((2*si+1)*256 + krow)*256 + j];
    v = neg ? (wi - ww) : (wi + ww);
  } else {
    v = -2.f * wg[(size_t)((sg-8)*2*256 + k)*256 + j];
  }
  WT[idx] = f2h(v);
}

// W_eff (fp16, [b][j=n][c=k])
__global__ __launch_bounds__(256) void k_prep_weff(const float* __restrict__ wg,
                                                   const float* __restrict__ m,
                                                   unsigned short* __restrict__ WT){
  int b = blockIdx.x >> 8, c = blockIdx.x & 255, j = threadIdx.x;
  float acc = 0.f;
  #pragma unroll
  for (int si=0; si<2; ++si){
    int s = si+1;
    int cm = (c - s) & 255, cp = (c + s) & 255;
    float wi_c  = wg[(size_t)((2*si)*256 + c)*256 + j];
    float ww_c  = wg[(size_t)((2*si+1)*256 + c)*256 + j];
    float wi_cp = wg[(size_t)((2*si)*256 + cp)*256 + j];
    float ww_cp = wg[(size_t)((2*si+1)*256 + cp)*256 + j];
    acc += m[b*256+cm]*(wi_c+ww_c) + m[b*256+cp]*(wi_cp-ww_cp);
  }
  WT[(size_t)b*65536 + (size_t)j*256 + c] = f2h(acc);
}

// w_gate rows 256-511 (g_feat part) -> fp16 panels [8 k32][4 q][256 n][8 e]
__global__ __launch_bounds__(256) void k_prep_wgg(const float* __restrict__ wg,
                                                  unsigned short* __restrict__ WT){
  int idx = blockIdx.x*256 + threadIdx.x;     // 65536
  int e = idx&7, n=(idx>>3)&255, q=(idx>>11)&3, k32=idx>>13;
  int k = k32*32 + q*8 + e;
  WT[idx] = f2h(wg[(size_t)(256+k)*256 + n]);
}

// ---------------- fused depthwise 3x3 + 3x3 + BN + SiLU - z_det
__global__ __launch_bounds__(256) void k_dwf(const unsigned short* __restrict__ A3,
                                             const float* __restrict__ w1g,
                                             const float* __restrict__ w2g,
                                             const float* __restrict__ bg,
                                             const float* __restrict__ bm_,
                                             const float* __restrict__ bv,
                                             const unsigned short* __restrict__ zdet,
                                             unsigned short* __restrict__ zcx){
  __shared__ unsigned short t0[12800];   // [20][20][32] bf16
  __shared__ unsigned short t1[10368];   // [18][18][32] fp16
  int t = blockIdx.x;
  int img = t >> 6, ty = (t>>3)&7, tx = t&7;
  int c0 = blockIdx.y*32;
  int tid = threadIdx.x;
  int ch = tid & 31;
  int c = c0 + ch;
  for (int v = tid; v < 3200; v += 256){
    int py = v / 160, rem = v - py*160;
    int px = rem >> 3, ch4 = (rem & 7)*4;
    int gpy = ty*16 - 2 + py, gpx = tx*16 - 2 + px;
    ushort4v val = {0,0,0,0};
    if ((unsigned)gpy < 128u && (unsigned)gpx < 128u){
      size_t gp = (size_t)(img*16384 + gpy*128 + gpx);
      val = *(const ushort4v*)&A3[gp*512 + c0 + ch4];
    }
    *(ushort4v*)&t0[(py*20+px)*32 + ch4] = val;
  }
  float w1[9], w2[9];
  #pragma unroll
  for (int k=0;k<9;k++){ w1[k] = w1g[k*256 + c]; w2[k] = w2g[k*256 + c]; }
  __syncthreads();
  for (int p = tid>>5; p < 324; p += 8){
    int py = p / 18, px = p - py*18;
    int gpy = ty*16 - 1 + py, gpx = tx*16 - 1 + px;
    float acc = 0.f;
    #pragma unroll
    for (int dy=0; dy<3; ++dy)
      #pragma unroll
      for (int dx=0; dx<3; ++dx)
        acc += bf2f(t0[((py+dy)*20 + px+dx)*32 + ch]) * w1[dy*3+dx];
    bool valid = ((unsigned)gpy < 128u) && ((unsigned)gpx < 128u);
    t1[p*32 + ch] = valid ? f2h(acc) : (unsigned short)0;
  }
  __syncthreads();
  float bmv = bm_[c];
  float rsbg = rsqrtf(bv[c] + 1e-3f) * bg[c];
  for (int p = tid>>5; p < 256; p += 8){
    int py = p >> 4, px = p & 15;
    float acc = 0.f;
    #pragma unroll
    for (int dy=0; dy<3; ++dy)
      #pragma unroll
      for (int dx=0; dx<3; ++dx)
        acc += h2f(t1[((py+dy)*18 + px+dx)*32 + ch]) * w2[dy*3+dx];
    float tv = (acc - bmv) * rsbg;
    float sv = tv / (1.f + __expf(-tv));
    size_t gp = (size_t)(img*16384 + (ty*16+py)*128 + tx*16+px);
    float z = sv - h2f(zdet[gp*256 + c]);
    zcx[gp*256 + c] = f2h(z);
  }
}

// ---------------- dual-output MFMA GEMM: z_det and gate_x, K=256
// grid (4, 512): x = n-block (0,1 -> z_det cols; 2,3 -> gate_x cols), y = m-block
__global__ __launch_bounds__(256) void k_gemmD(const unsigned short* __restrict__ A,
                                               const unsigned short* __restrict__ Bt1,
                                               const unsigned short* __restrict__ Bt2,
                                               unsigned short* __restrict__ o1,
                                               unsigned short* __restrict__ o2){
  __shared__ unsigned short As[128*64];
  __shared__ unsigned short Bss[128*64];
  const int tid=threadIdx.x, lane=tid&63, wid=tid>>6;
  const int nb = blockIdx.x;
  const int bm = blockIdx.y*128;
  const unsigned short* Bt = (nb<2)? Bt1 : Bt2;
  unsigned short* outh = (nb<2)? o1 : o2;
  const int bn = (nb&1)*128;
  const int wr = wid>>1, wc = wid&1;
  f32x4 acc[4][4] = {};
  const int srow = lane>>3;
  const int skc  = ((lane&7) ^ srow) * 8;
  for (int t=0; t<4; ++t){
    int k0 = t*64;
    #pragma unroll
    for (int i=0;i<4;i++){
      int q = wid*4 + i;
      int row = q*8 + srow;
      gll16(A  + (size_t)(bm+row)*512 + k0 + skc, &As[q*512]);
      gll16(Bt + (size_t)(bn+row)*256 + k0 + skc, &Bss[q*512]);
    }
    __syncthreads();
    #pragma unroll
    for (int kk=0; kk<2; ++kk){
      bf16x8 af[4], bfr[4];
      #pragma unroll
      for (int i=0;i<4;i++){
        int rl = wr*64 + i*16 + (lane&15);
        int kc = (kk*32 + (lane>>4)*8) ^ ((rl&7)*8);
        af[i]  = *(const bf16x8*)&As[rl*64 + kc];
        int cl = wc*64 + i*16 + (lane&15);
        int kcb = (kk*32 + (lane>>4)*8) ^ ((cl&7)*8);
        bfr[i] = *(const bf16x8*)&Bss[cl*64 + kcb];
      }
      #pragma unroll
      for (int i=0;i<4;i++)
        #pragma unroll
        for (int j=0;j<4;j++)
          acc[i][j] = __builtin_amdgcn_mfma_f32_16x16x32_bf16(af[i], bfr[j], acc[i][j], 0,0,0);
    }
    __syncthreads();
  }
  #pragma unroll
  for (int i=0;i<4;i++)
    #pragma unroll
    for (int j=0;j<4;j++)
      #pragma unroll
      for (int r=0;r<4;r++){
        int row = bm + wr*64 + i*16 + (lane>>4)*4 + r;
        int col = bn + wc*64 + j*16 + (lane&15);
        outh[(size_t)row*256 + col] = f2h(acc[i][j][r]);
      }
}

// ---------------- fused geo GEMM (R3 phase-1, 148us) + gate GEMM + final mix
template<int S>
__device__ __attribute__((always_inline)) ushort8 shsel(ushort8 hi, ushort8 lo){
  ushort8 r;
  if constexpr (S==0) return hi;
  #pragma unroll
  for (int e=0;e<8;e++) r[e] = (e<S) ? lo[8-S+e] : hi[e-S];
  return r;
}

template<int SEG>
__device__ __attribute__((always_inline)) f16x8 gen2(ushort8 zdh, ushort8 zdl,
      ushort8 zch, ushort8 zcl, ushort8 zcu){
  if constexpr (SEG==10) return __builtin_bit_cast(f16x8, zdh);
  ushort8 sel;
  if constexpr      (SEG==0) sel = shsel<1>(zch, zcl);
  else if constexpr (SEG==1) sel = shsel<7>(zcu, zch);
  else if constexpr (SEG==2) sel = shsel<2>(zch, zcl);
  else if constexpr (SEG==3) sel = shsel<6>(zcu, zch);
  else if constexpr (SEG==4) sel = shsel<4>(zch, zcl);
  else if constexpr (SEG==5) sel = shsel<4>(zcu, zch);
  else if constexpr (SEG==6) sel = zcl;
  else if constexpr (SEG==7) sel = zcu;
  else if constexpr (SEG==8) sel = shsel<1>(zdh, zdl);
  else                       sel = shsel<2>(zdh, zdl);
  return __builtin_bit_cast(f16x8, zdh) * __builtin_bit_cast(f16x8, sel);
}

__global__ __launch_bounds__(256) void k_geo(const unsigned short* __restrict__ zd,
                                             const unsigned short* __restrict__ zc,
                                             const unsigned short* __restrict__ WT_all,
                                             const unsigned short* __restrict__ WeffT,
                                             const unsigned short* __restrict__ WGGP,
                                             const unsigned short* __restrict__ GXB,
                                             const unsigned short* __restrict__ A3,
                                             const float* __restrict__ x,
                                             const float* __restrict__ gls,
                                             float* __restrict__ out){
  __shared__ unsigned short Bs[3][8192];     // ring-3 panels; reused as Gs in phase 2
  const int tid = threadIdx.x, lane = tid&63, wid = tid>>6;
  const int bm = blockIdx.x*64;
  const int img = blockIdx.x >> 8;
  const int wr = wid>>1, wc = wid&1;         // wave: 32 rows x 128 cols
  f32x4 acc0[8] = {}, acc1[8] = {};

  const int s4 = tid & 3;
  int inv[4];
  #pragma unroll
  for (int g=0; g<4; ++g){
    int n = g*64 + (tid>>2);
    int sw = (n + (n>>2)) & 3;
    inv[g] = n*256 + ((s4^sw)<<3);
  }
  int roff[8];
  #pragma unroll
  for (int fj=0; fj<8; ++fj){
    int n = wc*128 + fj*16 + (lane&15);
    int sw = (n + (n>>2)) & 3;
    roff[fj] = n*32 + (((lane>>4) ^ sw) << 3);
  }

  const int m0 = bm + wr*32 + (lane&15);
  const unsigned short* zdr0 = zd + (size_t)m0*256;
  const unsigned short* zdr1 = zdr0 + 16*256;
  const unsigned short* zcr0 = zc + (size_t)m0*256;
  const unsigned short* zcr1 = zcr0 + 16*256;

  ushort8 zdh0,zdl0,zch0,zcl0,zcu0, zdh1,zdl1,zch1,zcl1,zcu1;
  int cur = 0;

#define STAGE(BUF, SP, KK) { \
    const unsigned short* Wb = ((SP)<10) ? (WT_all + (SP)*65536) : (WeffT + (size_t)img*65536); \
    const unsigned short* Wk = Wb + (KK)*32; \
    gll16(Wk + inv[0], &Bs[BUF][0*2048 + wid*512]); \
    gll16(Wk + inv[1], &Bs[BUF][1*2048 + wid*512]); \
    gll16(Wk + inv[2], &Bs[BUF][2*2048 + wid*512]); \
    gll16(Wk + inv[3], &Bs[BUF][3*2048 + wid*512]); \
  }

  STAGE(0, 0, 0);
  STAGE(1, 1, 0);

#define STEP(P) { \
    asm volatile("s_waitcnt vmcnt(4)" ::: "memory"); \
    __builtin_amdgcn_s_barrier(); \
    if constexpr ((P)==0){ \
      int kc = k32*32 + (lane>>4)*8; \
      int kl = (kc-8)&255, ku = (kc+8)&255; \
      zdh0 = *(const ushort8*)(zdr0 + kc); zdl0 = *(const ushort8*)(zdr0 + kl); \
      zch0 = *(const ushort8*)(zcr0 + kc); zcl0 = *(const ushort8*)(zcr0 + kl); \
      zcu0 = *(const ushort8*)(zcr0 + ku); \
      zdh1 = *(const ushort8*)(zdr1 + kc); zdl1 = *(const ushort8*)(zdr1 + kl); \
      zch1 = *(const ushort8*)(zcr1 + kc); zcl1 = *(const ushort8*)(zcr1 + kl); \
      zcu1 = *(const ushort8*)(zcr1 + ku); \
    } \
    __builtin_amdgcn_sched_barrier(0); \
    { constexpr int s2 = ((P)+2 <= 10) ? (P)+2 : (P)+2-11; \
      int k2 = k32 + (((P)+2 > 10) ? 1 : 0); if (k2 > 7) k2 = 7; \
      int nbuf = cur+2; if (nbuf >= 3) nbuf -= 3; \
      STAGE(nbuf, s2, k2); } \
    __builtin_amdgcn_sched_barrier(0); \
    f16x8 af0 = gen2<(P)>(zdh0,zdl0,zch0,zcl0,zcu0); \
    f16x8 af1 = gen2<(P)>(zdh1,zdl1,zch1,zcl1,zcu1); \
    const unsigned short* bp = &Bs[cur][0]; \
    __builtin_amdgcn_s_setprio(1); \
    _Pragma("unroll") \
    for (int fj=0; fj<8; ++fj){ \
      f16x8 bfr = *(const f16x8*)&bp[roff[fj]]; \
      acc0[fj] = __builtin_amdgcn_mfma_f32_16x16x32_f16(af0, bfr, acc0[fj], 0,0,0); \
      acc1[fj] = __builtin_amdgcn_mfma_f32_16x16x32_f16(af1, bfr, acc1[fj], 0,0,0); \
    } \
    __builtin_amdgcn_s_setprio(0); \
    cur = cur+1; if (cur >= 3) cur -= 3; \
  }

  for (int k32=0; k32<8; ++k32){
    STEP(0) STEP(1) STEP(2) STEP(3) STEP(4) STEP(5)
    STEP(6) STEP(7) STEP(8) STEP(9) STEP(10)
  }
#undef STEP
#undef STAGE

  // ---- phase 2: gate GEMM + final mix. Reuse Bs memory as Gs[64][256] fp16.
  asm volatile("s_waitcnt vmcnt(0)" ::: "memory");
  __syncthreads();                             // all panel stages landed, all reads done
  unsigned short* Gs = &Bs[0][0];

  #pragma unroll
  for (int fj=0; fj<8; ++fj)
    #pragma unroll
    for (int r=0; r<4; ++r){
      int col = wc*128 + fj*16 + (lane&15);
      int rl0 = wr*32 + (lane>>4)*4 + r;
      int rl1 = rl0 + 16;
      Gs[rl0*256 + (col ^ ((rl0&7)<<3))] = f2h(acc0[fj][r]);
      Gs[rl1*256 + (col ^ ((rl1&7)<<3))] = f2h(acc1[fj][r]);
    }
  {
    f32x4 zz = {};
    #pragma unroll
    for (int fj=0; fj<8; ++fj){ acc0[fj] = zz; acc1[fj] = zz; }
  }
  __syncthreads();

  // gate-g GEMM: acc = Gs[64 rows][256 K] @ WGGP (K=256), fragments from L2
  const int q = lane>>4;
  #pragma unroll
  for (int k32=0; k32<8; ++k32){
    int kc = k32*32 + q*8;
    int ra0 = wr*32 + (lane&15);
    int ra1 = ra0 + 16;
    f16x8 af0 = *(const f16x8*)&Gs[ra0*256 + (kc ^ ((ra0&7)<<3))];
    f16x8 af1 = *(const f16x8*)&Gs[ra1*256 + (kc ^ ((ra1&7)<<3))];
    const unsigned short* wp = WGGP + k32*8192 + q*2048 + (wc*128 + (lane&15))*8;
    #pragma unroll
    for (int fj=0; fj<8; ++fj){
      f16x8 bfr = *(const f16x8*)(wp + fj*128);
      acc0[fj] = __builtin_amdgcn_mfma_f32_16x16x32_f16(af0, bfr, acc0[fj], 0,0,0);
      acc1[fj] = __builtin_amdgcn_mfma_f32_16x16x32_f16(af1, bfr, acc1[fj], 0,0,0);
    }
  }

  // epilogue: alpha = sigmoid(gate_x + gate_g); out = x + (silu(xn) + alpha*gf)*gamma
  #pragma unroll
  for (int fj=0; fj<8; ++fj)
    #pragma unroll
    for (int r=0; r<4; ++r){
      int col = wc*128 + fj*16 + (lane&15);
      float gm = gls[col];
      #pragma unroll
      for (int g2=0; g2<2; ++g2){
        int rl = wr*32 + (lane>>4)*4 + r + g2*16;
        int row = bm + rl;
        float gf = h2f(Gs[rl*256 + (col ^ ((rl&7)<<3))]);
        float gv = (g2 ? acc1[fj][r] : acc0[fj][r]) + h2f(GXB[(size_t)row*256 + col]);
        float alpha = 1.f/(1.f+__expf(-gv));
        float xn = bf2f(A3[(size_t)row*512 + col]);
        float sl = xn/(1.f+__expf(-xn));
        out[(size_t)row*256 + col] = x[(size_t)row*256 + col] + (sl + alpha*gf)*gm;
      }
    }
}

extern "C" void kernel_launch(void* const* d_in, const int* in_sizes, int n_in,
                              void* d_out, int out_size, void* d_ws, size_t ws_size,
                              hipStream_t stream){
  (void)in_sizes; (void)n_in; (void)out_size; (void)ws_size;
  const float* x    = (const float*)d_in[0];
  const float* lng  = (const float*)d_in[1];
  const float* wdet = (const float*)d_in[2];
  const float* dw1  = (const float*)d_in[3];
  const float* dw2  = (const float*)d_in[4];
  const float* bng  = (const float*)d_in[5];
  const float* bnm  = (const float*)d_in[6];
  const float* bnv  = (const float*)d_in[7];
  const float* wloc = (const float*)d_in[8];
  const float* wglo = (const float*)d_in[9];
  const float* wgat = (const float*)d_in[10];
  const float* gls  = (const float*)d_in[11];
  float* out = (float*)d_out;
  char* ws = (char*)d_ws;

  unsigned short* A3     = (unsigned short*)(ws);                 // 64 MB [65536][512] bf16
  unsigned short* ZDET   = (unsigned short*)(ws + 67108864);      // 32 MB fp16
  unsigned short* GXB    = (unsigned short*)(ws + 100663296);     // 32 MB fp16 gate_x
  unsigned short* ZCX    = (unsigned short*)(ws + 134217728);     // 32 MB fp16
  unsigned short* WTALL  = (unsigned short*)(ws + 167772160);     // 1.25 MB fp16 [10][n][k]
  unsigned short* WEFFT  = (unsigned short*)(ws + 169213952);     // 0.5 MB fp16 [b][n][k]
  unsigned short* WDETT  = (unsigned short*)(ws + 169738240);     // 128 KB bf16
  unsigned short* WGXT   = (unsigned short*)(ws + 169869312);     // 128 KB bf16
  unsigned short* WGGP   = (unsigned short*)(ws + 170000384);     // 128 KB fp16 panels
  float* PSUM  = (float*)(ws + 170131456);                        // 256 KB
  float* MMEAN = (float*)(ws + 170393600);                        // 4 KB

  k_ln<<<16384, 256, 0, stream>>>(x, lng, A3);
  k_cm1<<<256, 256, 0, stream>>>(A3, PSUM);
  k_cm2<<<4, 256, 0, stream>>>(PSUM, MMEAN);
  k_prep_nt<<<256, 256, 0, stream>>>(wdet, WDETT, 256);
  k_prep_nt<<<256, 256, 0, stream>>>(wgat, WGXT, 256);
  k_prep_wgg<<<256, 256, 0, stream>>>(wgat, WGGP);
  k_prep_geoT<<<2560, 256, 0, stream>>>(wloc, wglo, WTALL);
  k_prep_weff<<<1024, 256, 0, stream>>>(wglo, MMEAN, WEFFT);
  k_gemmD<<<dim3(4,512), 256, 0, stream>>>(A3, WDETT, WGXT, ZDET, GXB);
  k_dwf<<<dim3(256,8), 256, 0, stream>>>(A3, dw1, dw2, bng, bnm, bnv, ZDET, ZCX);
  k_geo<<<1024, 256, 0, stream>>>(ZDET, ZCX, WTALL, WEFFT, WGGP, GXB, A3, x, gls, out);
}